// Round 2
// baseline (211.147 us; speedup 1.0000x reference)
//
#include <hip/hip_runtime.h>

typedef _Float16 half_t;
typedef _Float16 half8  __attribute__((ext_vector_type(8)));
typedef _Float16 half4v __attribute__((ext_vector_type(4)));
typedef float    f32x16 __attribute__((ext_vector_type(16)));
typedef float    f32x4  __attribute__((ext_vector_type(4)));

#define DEVI static __device__ __forceinline__

constexpr int B_  = 16384;
constexpr int T_  = 28;
constexpr int IN_ = 28;
constexpr int H_  = 128;
constexpr int C_  = 11;
constexpr int BT  = 64;    // batch rows per block (grid = 256 blocks = 1/CU)
constexpr int HSTR = 136;  // LDS stride (halves) for h: 272B rows, 16B-aligned, balanced banks
constexpr int XSTR = 40;   // LDS stride (halves) for x tile (K padded 28->32)

struct SMem {
  alignas(16) half_t h[3][BT * HSTR];  // per-layer recurrent state [b][n]
  alignas(16) half_t xin[BT * XSTR];   // staged x_t tile [b][k], fp16, cols 28..31 stay 0
  alignas(16) float  bias[3][H_];      // combined bih+bhh per layer
};

DEVI f32x16 mfma(half8 a, half8 b, f32x16 c) {
  return __builtin_amdgcn_mfma_f32_32x32x16_f16(a, b, c, 0, 0, 0);
}

// Load A-fragments for one 32-row m-tile of a 128x128 row-major fp32 weight matrix.
// A layout (32x32x16 f16): lane holds A[m=lane&31][k=(lane>>5)*8+j], j=0..7.
DEVI void loadw(half8 d[8], const float* __restrict__ w, int m, int hf) {
  const float* p = w + m * H_ + hf * 8;
#pragma unroll
  for (int kc = 0; kc < 8; ++kc) {
    half8 f;
#pragma unroll
    for (int j = 0; j < 8; ++j) f[j] = (half_t)p[kc * 16 + j];
    d[kc] = f;
  }
}

// pre[m-tile][batch 0..63] = Wih . in^T + Whh . hprev^T  (both accs, K fully unrolled)
template <int KIN, int ISTR>
DEVI void mmstep(const half_t* __restrict__ inb, const half_t* __restrict__ hp,
                 const half8* awi, const half8* awh,
                 f32x16& acc0, f32x16& acc1, int l31, int hf) {
  f32x16 a0 = {};
  f32x16 a1 = {};
#pragma unroll
  for (int kc = 0; kc < KIN; ++kc) {
    half8 b0 = *(const half8*)&inb[(l31) * ISTR + kc * 16 + hf * 8];
    half8 b1 = *(const half8*)&inb[(32 + l31) * ISTR + kc * 16 + hf * 8];
    a0 = mfma(awi[kc], b0, a0);
    a1 = mfma(awi[kc], b1, a1);
  }
#pragma unroll
  for (int kc = 0; kc < 8; ++kc) {
    half8 b0 = *(const half8*)&hp[(l31) * HSTR + kc * 16 + hf * 8];
    half8 b1 = *(const half8*)&hp[(32 + l31) * HSTR + kc * 16 + hf * 8];
    a0 = mfma(awh[kc], b0, a0);
    a1 = mfma(awh[kc], b1, a1);
  }
  acc0 = a0;
  acc1 = a1;
}

// h = relu(pre + bias) back to LDS.  C/D layout (HW-verified m74/m101):
// col = lane&31 (batch), row = (reg&3) + 8*(reg>>2) + 4*(lane>>5)  -> 4 contiguous rows/quad.
DEVI void epi(half_t* __restrict__ hout, const float* __restrict__ bl,
              f32x16 acc0, f32x16 acc1, int wid, int l31, int hf) {
#pragma unroll
  for (int rq = 0; rq < 4; ++rq) {
    const int n0 = wid * 32 + rq * 8 + hf * 4;
    const f32x4 b4 = *(const f32x4*)&bl[n0];
    half4v h4a, h4b;
#pragma unroll
    for (int ri = 0; ri < 4; ++ri) {
      h4a[ri] = (half_t)fmaxf(acc0[rq * 4 + ri] + b4[ri], 0.0f);
      h4b[ri] = (half_t)fmaxf(acc1[rq * 4 + ri] + b4[ri], 0.0f);
    }
    *(half4v*)&hout[(l31) * HSTR + n0] = h4a;
    *(half4v*)&hout[(32 + l31) * HSTR + n0] = h4b;
  }
}

__global__ __launch_bounds__(256, 1)
void rnn_fused(const float* __restrict__ x,
               const float* __restrict__ wih0, const float* __restrict__ whh0,
               const float* __restrict__ bih0, const float* __restrict__ bhh0,
               const float* __restrict__ wih1, const float* __restrict__ whh1,
               const float* __restrict__ bih1, const float* __restrict__ bhh1,
               const float* __restrict__ wih2, const float* __restrict__ whh2,
               const float* __restrict__ bih2, const float* __restrict__ bhh2,
               const float* __restrict__ fcw, const float* __restrict__ fcb,
               float* __restrict__ out)
{
  __shared__ SMem sm;
  const int tid  = threadIdx.x;
  const int b0   = blockIdx.x * BT;
  const int lane = tid & 63;
  const int wid  = tid >> 6;    // m-tile index: hidden rows [wid*32, wid*32+32)
  const int l31  = lane & 31;
  const int hf   = lane >> 5;
  const int m    = wid * 32 + l31;

  // ---- register-resident weights for ALL layers (held across all 28 steps) ----
  half8 ah0[8], ai1[8], ah1[8], ai2[8], ah2[8], ai0[2];
  loadw(ah0, whh0, m, hf);
  loadw(ai1, wih1, m, hf);
  loadw(ah1, whh1, m, hf);
  loadw(ai2, wih2, m, hf);
  loadw(ah2, whh2, m, hf);
#pragma unroll
  for (int kc = 0; kc < 2; ++kc) {   // wih0: K=28 padded to 32
    half8 f;
#pragma unroll
    for (int j = 0; j < 8; ++j) {
      const int k = kc * 16 + hf * 8 + j;
      f[j] = (k < IN_) ? (half_t)wih0[m * IN_ + k] : (half_t)0.0f;
    }
    ai0[kc] = f;
  }

  // ---- zero h[0..2] + xin; stage combined biases ----
  for (int i = tid; i < (3 * BT * HSTR + BT * XSTR) / 2; i += 256)
    ((unsigned int*)sm.h)[i] = 0u;
  if (tid < H_) {
    sm.bias[0][tid] = bih0[tid] + bhh0[tid];
    sm.bias[1][tid] = bih1[tid] + bhh1[tid];
    sm.bias[2][tid] = bih2[tid] + bhh2[tid];
  }
  __syncthreads();

  // ---- x prefetch: thread covers row=tid>>2, 7 floats at col (tid&3)*7 ----
  const int prow = tid >> 2, pc0 = (tid & 3) * 7;
  const float* xrow = x + (size_t)(b0 + prow) * T_ * IN_ + pc0;
  float xr[7];
#pragma unroll
  for (int j = 0; j < 7; ++j) xr[j] = xrow[j];   // t = 0

  f32x16 acc0, acc1;
  for (int t = 0; t < T_; ++t) {
#pragma unroll
    for (int j = 0; j < 7; ++j) sm.xin[prow * XSTR + pc0 + j] = (half_t)xr[j];
    __syncthreads();                                   // xin ready
    mmstep<2, XSTR>(sm.xin, sm.h[0], ai0, ah0, acc0, acc1, l31, hf);
    if (t + 1 < T_) {                                  // prefetch x_{t+1} (overlaps L1/L2)
      const float* xn = xrow + (t + 1) * IN_;
#pragma unroll
      for (int j = 0; j < 7; ++j) xr[j] = xn[j];
    }
    __syncthreads();                                   // all reads of h0_old done
    epi(sm.h[0], sm.bias[0], acc0, acc1, wid, l31, hf);
    __syncthreads();                                   // h0_new visible
    mmstep<8, HSTR>(sm.h[0], sm.h[1], ai1, ah1, acc0, acc1, l31, hf);
    __syncthreads();
    epi(sm.h[1], sm.bias[1], acc0, acc1, wid, l31, hf);
    __syncthreads();
    mmstep<8, HSTR>(sm.h[1], sm.h[2], ai2, ah2, acc0, acc1, l31, hf);
    __syncthreads();
    epi(sm.h[2], sm.bias[2], acc0, acc1, wid, l31, hf);
    // no trailing sync needed: next use of h2 is L2's read at t+1, 5 syncs away
  }
  __syncthreads();   // h2 final visible for FC

  // ---- FC head: out[b][c] = h2_last[b] . fcw[c] + fcb[c] ----
  const int row = tid >> 2, q = tid & 3;
  for (int c = q; c < C_; c += 4) {
    float s = fcb[c];
    const float* wp = fcw + c * H_;
#pragma unroll
    for (int k = 0; k < H_; k += 8) {
      const half8 hv = *(const half8*)&sm.h[2][row * HSTR + k];
#pragma unroll
      for (int j = 0; j < 8; ++j) s += (float)hv[j] * wp[k + j];
    }
    out[(size_t)(b0 + row) * C_ + c] = s;
  }
}

extern "C" void kernel_launch(void* const* d_in, const int* in_sizes, int n_in,
                              void* d_out, int out_size, void* d_ws, size_t ws_size,
                              hipStream_t stream)
{
  const float* x    = (const float*)d_in[0];
  const float* wih0 = (const float*)d_in[1];
  const float* whh0 = (const float*)d_in[2];
  const float* bih0 = (const float*)d_in[3];
  const float* bhh0 = (const float*)d_in[4];
  const float* wih1 = (const float*)d_in[5];
  const float* whh1 = (const float*)d_in[6];
  const float* bih1 = (const float*)d_in[7];
  const float* bhh1 = (const float*)d_in[8];
  const float* wih2 = (const float*)d_in[9];
  const float* whh2 = (const float*)d_in[10];
  const float* bih2 = (const float*)d_in[11];
  const float* bhh2 = (const float*)d_in[12];
  const float* fcw  = (const float*)d_in[13];
  const float* fcb  = (const float*)d_in[14];
  float* out = (float*)d_out;

  rnn_fused<<<B_ / BT, 256, 0, stream>>>(x,
      wih0, whh0, bih0, bhh0,
      wih1, whh1, bih1, bhh1,
      wih2, whh2, bih2, bhh2,
      fcw, fcb, out);
}